// Round 7
// baseline (1316.769 us; speedup 1.0000x reference)
//
#include <hip/hip_runtime.h>

// GCN encoder: 2x GCNConv (symmetric norm, self-loops) + global mean pool.
// N=100000, E=1600000, F_IN=64, H=128, O=64, B=64.
//
// R3: k_cnt atomics -> binary search (-623us, matched).
// R5: 4-edge MLP batching: NULL result (-5%). Falsified latency theory.
// R7: random 256B gathers are a granularity/BW wall (FETCH 211MB vs 39MB
//     compulsory). Counting-sort edges by SRC once; both edge passes then
//     READ sequentially (row reused across its sorted run) and SCATTER with
//     fire-and-forget atomics. dinv[d] factored out of pass1 so it has zero
//     per-edge random reads; pass2 gathers 8B/edge from L2-resident pk table.
//     h1 stored bf16 to keep ws under budget with sort arrays.

#define NN 100000
#define NE 1600000
#define FI 64
#define FH 128
#define FO 64
#define NB 64
#define SCAN_BLKS 98  // ceil(100000/1024)

// ---------------- init: zero int-degree, hist(cursor), pooled sums ----------
__global__ __launch_bounds__(256) void k_init(int* __restrict__ degi,
                                              int* __restrict__ hist,
                                              float* __restrict__ out_sums) {
  int i = blockIdx.x * 256 + threadIdx.x;
  if (i < NN) { degi[i] = 0; hist[i] = 0; }
  if (i < NB * FO) out_sums[i] = 0.0f;
}

// ---------------- one pass over edges: dst-degree + src-histogram -----------
__global__ __launch_bounds__(256) void k_deg_hist(const int* __restrict__ es,
                                                  const int* __restrict__ ed,
                                                  int* __restrict__ degi,
                                                  int* __restrict__ hist) {
  int stride = gridDim.x * 256;
  for (int e = blockIdx.x * 256 + threadIdx.x; e < NE; e += stride) {
    atomicAdd(&degi[ed[e]], 1);
    atomicAdd(&hist[es[e]], 1);
  }
}

// ---------------- dinv = rsqrt(1+indeg); pk[i] = (dinv, bits(batch)) --------
__global__ __launch_bounds__(256) void k_dinv_pk(const int* __restrict__ degi,
                                                 const int* __restrict__ batch,
                                                 float* __restrict__ dinv,
                                                 float2* __restrict__ pk) {
  int i = blockIdx.x * 256 + threadIdx.x;
  if (i < NN) {
    float di = rsqrtf(1.0f + (float)degi[i]);
    dinv[i] = di;
    pk[i] = make_float2(di, __int_as_float(batch[i]));
  }
}

// ---------------- exclusive scan of hist -> row_ptr (3 kernels) -------------
__global__ __launch_bounds__(1024) void k_scan1(const int* __restrict__ hist,
                                                int* __restrict__ row_ptr,
                                                int* __restrict__ blksum) {
  __shared__ int s[1024];
  int tid = threadIdx.x;
  int i = blockIdx.x * 1024 + tid;
  int v = (i < NN) ? hist[i] : 0;
  s[tid] = v;
  __syncthreads();
  for (int off = 1; off < 1024; off <<= 1) {
    int t = (tid >= off) ? s[tid - off] : 0;
    __syncthreads();
    s[tid] += t;
    __syncthreads();
  }
  if (i < NN) row_ptr[i] = s[tid] - v;  // exclusive, pre-block-offset
  if (tid == 1023) blksum[blockIdx.x] = s[1023];
}

__global__ __launch_bounds__(128) void k_scan2(int* __restrict__ blksum) {
  if (threadIdx.x == 0) {
    int run = 0;
    for (int i = 0; i < SCAN_BLKS; i++) { int t = blksum[i]; blksum[i] = run; run += t; }
  }
}

__global__ __launch_bounds__(1024) void k_scan3(int* __restrict__ row_ptr,
                                                const int* __restrict__ blksum,
                                                int* __restrict__ cursor) {
  int i = blockIdx.x * 1024 + threadIdx.x;
  if (i < NN) {
    int rp = row_ptr[i] + blksum[blockIdx.x];
    row_ptr[i] = rp;
    cursor[i] = rp;
  }
  if (i == 0) row_ptr[NN] = NE;
}

// ---------------- placement: sd[pos] = dst, grouped by src ------------------
__global__ __launch_bounds__(256) void k_place(const int* __restrict__ es,
                                               const int* __restrict__ ed,
                                               int* __restrict__ cursor,
                                               int* __restrict__ sd) {
  int stride = gridDim.x * 256;
  for (int e = blockIdx.x * 256 + threadIdx.x; e < NE; e += stride) {
    int s = es[e];
    int pos = atomicAdd(&cursor[s], 1);
    sd[pos] = ed[e];
  }
}

// ---------------- zero m buffer ---------------------------------------------
__global__ __launch_bounds__(256) void k_zero(float4* __restrict__ p, int n4) {
  int i = blockIdx.x * 256 + threadIdx.x;
  if (i < n4) p[i] = make_float4(0.f, 0.f, 0.f, 0.f);
}

// ---------------- pass1: m[d] += dinv[s]*x[s] over src-sorted edges ---------
// wave per src row: row read once (sequential overall), per edge just one
// sequential 4B metadata read + one fire-and-forget 256B atomic scatter.
__global__ __launch_bounds__(256) void k_scatter(const int* __restrict__ row_ptr,
                                                 const int* __restrict__ sd,
                                                 const float* __restrict__ dinv,
                                                 const float* __restrict__ x,
                                                 float* __restrict__ m) {
  int lane = threadIdx.x & 63;
  int wid = (blockIdx.x * 256 + threadIdx.x) >> 6;
  int nw = (gridDim.x * 256) >> 6;
  for (int s = wid; s < NN; s += nw) {
    int rp0 = row_ptr[s], rp1 = row_ptr[s + 1];
    if (rp0 == rp1) continue;
    float xr = x[(size_t)s * FI + lane] * dinv[s];
    for (int j0 = rp0; j0 < rp1; j0 += 64) {
      int li = j0 + lane;
      int sdv = (li < rp1) ? sd[li] : 0;
      int cl = min(64, rp1 - j0);
      for (int j = 0; j < cl; j++) {
        int d = __builtin_amdgcn_readlane(sdv, j);
        atomicAdd(&m[(size_t)d * FI + lane], xr);
      }
    }
  }
}

// ---------------- pass1 finish: aggx = dinv*(m + dinv*x) (elementwise) ------
__global__ __launch_bounds__(256) void k_aggx_fin(const float* __restrict__ x,
                                                  const float* __restrict__ dinv,
                                                  float* __restrict__ m) {
  int i = blockIdx.x * 256 + threadIdx.x;  // float4 index
  if (i < NN * (FI / 4)) {
    int node = i >> 4;
    float di = dinv[node];
    float4 xv = ((const float4*)x)[i];
    float4 mv = ((float4*)m)[i];
    mv.x = di * (mv.x + di * xv.x);
    mv.y = di * (mv.y + di * xv.y);
    mv.z = di * (mv.z + di * xv.z);
    mv.w = di * (mv.w + di * xv.w);
    ((float4*)m)[i] = mv;
  }
}

// ---------------- bf16 helpers ----------------------------------------------
__device__ __forceinline__ unsigned bf16rn(float f) {
  unsigned u = __float_as_uint(f);
  return (u + 0x7fffu + ((u >> 16) & 1u)) >> 16;
}
__device__ __forceinline__ float bf16lo(unsigned u) { return __uint_as_float(u << 16); }
__device__ __forceinline__ float bf16hi(unsigned u) { return __uint_as_float(u & 0xffff0000u); }

// ---------------- GEMM1: h1 = relu(aggx @ W1 + b1) -> bf16 ------------------
__global__ __launch_bounds__(256) void k_gemm1(const float* __restrict__ X,
                                               const float* __restrict__ W,
                                               const float* __restrict__ bias,
                                               unsigned* __restrict__ Y) {  // bf16 pairs
  __shared__ float XsT[FI][64];
  __shared__ float Ws[FI][FH];
  int tid = threadIdx.x;
  int row0 = blockIdx.x * 64;

  for (int i = tid; i < FI * FH / 4; i += 256)
    ((float4*)&Ws[0][0])[i] = ((const float4*)W)[i];

  for (int i = tid; i < 64 * (FI / 4); i += 256) {
    int c4 = i & 15;
    int r = i >> 4;
    int row = row0 + r;
    float4 v = (row < NN) ? ((const float4*)X)[row * (FI / 4) + c4]
                          : make_float4(0.f, 0.f, 0.f, 0.f);
    XsT[c4 * 4 + 0][r] = v.x; XsT[c4 * 4 + 1][r] = v.y;
    XsT[c4 * 4 + 2][r] = v.z; XsT[c4 * 4 + 3][r] = v.w;
  }
  __syncthreads();

  int tr = tid & 15, tc = tid >> 4;
  float acc[4][8];
#pragma unroll
  for (int i = 0; i < 4; i++)
#pragma unroll
    for (int j = 0; j < 8; j++) acc[i][j] = 0.f;

#pragma unroll 8
  for (int k = 0; k < FI; k++) {
    float4 a = *(const float4*)&XsT[k][tr * 4];
    float4 w0 = *(const float4*)&Ws[k][tc * 8];
    float4 w1 = *(const float4*)&Ws[k][tc * 8 + 4];
    float av[4] = {a.x, a.y, a.z, a.w};
    float wv[8] = {w0.x, w0.y, w0.z, w0.w, w1.x, w1.y, w1.z, w1.w};
#pragma unroll
    for (int i = 0; i < 4; i++)
#pragma unroll
      for (int j = 0; j < 8; j++) acc[i][j] += av[i] * wv[j];
  }

  float4 bv0 = *(const float4*)&bias[tc * 8];
  float4 bv1 = *(const float4*)&bias[tc * 8 + 4];
  float bb[8] = {bv0.x, bv0.y, bv0.z, bv0.w, bv1.x, bv1.y, bv1.z, bv1.w};
#pragma unroll
  for (int i = 0; i < 4; i++) {
    int row = row0 + tr * 4 + i;
    if (row < NN) {
      unsigned o[4];
#pragma unroll
      for (int j = 0; j < 4; j++) {
        float v0 = acc[i][2 * j] + bb[2 * j];
        float v1 = acc[i][2 * j + 1] + bb[2 * j + 1];
        v0 = v0 > 0.f ? v0 : 0.f;
        v1 = v1 > 0.f ? v1 : 0.f;
        o[j] = bf16rn(v0) | (bf16rn(v1) << 16);
      }
      // bf16 element index row*128 + tc*8 -> uint index row*64 + tc*4
      *(uint4*)&Y[(size_t)row * 64 + tc * 4] = make_uint4(o[0], o[1], o[2], o[3]);
    }
  }
}

// ---------------- GEMM2: h2 = h1(bf16) @ W2 ---------------------------------
__global__ __launch_bounds__(256) void k_gemm2(const unsigned* __restrict__ Xb,  // bf16 pairs
                                               const float* __restrict__ W,
                                               float* __restrict__ Y) {
  __shared__ float XsT[FH][64];
  __shared__ float Ws[FH][FO];
  int tid = threadIdx.x;
  int row0 = blockIdx.x * 64;

  for (int i = tid; i < FH * FO / 4; i += 256)
    ((float4*)&Ws[0][0])[i] = ((const float4*)W)[i];

  for (int i = tid; i < 64 * (FH / 8); i += 256) {  // 1024 iters: 8 bf16 each
    int c8 = (i & 15) * 8;
    int r = i >> 4;
    int row = row0 + r;
    uint4 q = (row < NN) ? *(const uint4*)&Xb[(size_t)row * 64 + (c8 >> 1)]
                         : make_uint4(0, 0, 0, 0);
    XsT[c8 + 0][r] = bf16lo(q.x); XsT[c8 + 1][r] = bf16hi(q.x);
    XsT[c8 + 2][r] = bf16lo(q.y); XsT[c8 + 3][r] = bf16hi(q.y);
    XsT[c8 + 4][r] = bf16lo(q.z); XsT[c8 + 5][r] = bf16hi(q.z);
    XsT[c8 + 6][r] = bf16lo(q.w); XsT[c8 + 7][r] = bf16hi(q.w);
  }
  __syncthreads();

  int tr = tid & 15, tc = tid >> 4;
  float acc[4][4];
#pragma unroll
  for (int i = 0; i < 4; i++)
#pragma unroll
    for (int j = 0; j < 4; j++) acc[i][j] = 0.f;

#pragma unroll 8
  for (int k = 0; k < FH; k++) {
    float4 a = *(const float4*)&XsT[k][tr * 4];
    float4 w = *(const float4*)&Ws[k][tc * 4];
    float av[4] = {a.x, a.y, a.z, a.w};
    float wv[4] = {w.x, w.y, w.z, w.w};
#pragma unroll
    for (int i = 0; i < 4; i++)
#pragma unroll
      for (int j = 0; j < 4; j++) acc[i][j] += av[i] * wv[j];
  }

#pragma unroll
  for (int i = 0; i < 4; i++) {
    int row = row0 + tr * 4 + i;
    if (row < NN)
      *(float4*)&Y[(size_t)row * FO + tc * 4] =
          make_float4(acc[i][0], acc[i][1], acc[i][2], acc[i][3]);
  }
}

// ---------------- node counts per graph: binary search on SORTED batch ------
__global__ __launch_bounds__(128) void k_cnt_bs(const int* __restrict__ batch,
                                                float* __restrict__ cnts) {
  __shared__ int lb[NB + 1];
  int b = threadIdx.x;
  if (b <= NB) {
    int lo = 0, hi = NN;
    while (lo < hi) {
      int mid = (lo + hi) >> 1;
      if (batch[mid] < b) lo = mid + 1; else hi = mid;
    }
    lb[b] = lo;
  }
  __syncthreads();
  if (b < NB) cnts[b] = (float)(lb[b + 1] - lb[b]);
}

// ---------------- pass2: pooled layer-2 aggregation over src-sorted edges ---
// wave per src row: h2 row read once; per 64-edge chunk one coalesced sd load
// + one 8B/lane vector gather of pk[d]; per edge 2 readlanes + 1 LDS atomic.
__global__ __launch_bounds__(512) void k_pool(const int* __restrict__ row_ptr,
                                              const int* __restrict__ sd,
                                              const float2* __restrict__ pk,
                                              const float* __restrict__ h2,
                                              float* __restrict__ out_sums) {
  __shared__ float lds[NB * FO];  // 16KB
  for (int i = threadIdx.x; i < NB * FO; i += 512) lds[i] = 0.f;
  __syncthreads();

  int lane = threadIdx.x & 63;
  int wid = (blockIdx.x * 512 + threadIdx.x) >> 6;
  int nw = (gridDim.x * 512) >> 6;
  for (int s = wid; s < NN; s += nw) {
    float2 ps = pk[s];
    float dis = ps.x;
    int bs = __float_as_int(ps.y);
    float hr = h2[(size_t)s * FO + lane] * dis;
    // self-loop: dinv_s^2 * h2[s] into bucket batch[s]
    atomicAdd(&lds[bs * FO + lane], hr * dis);
    int rp0 = row_ptr[s], rp1 = row_ptr[s + 1];
    for (int j0 = rp0; j0 < rp1; j0 += 64) {
      int li = j0 + lane;
      int dv = (li < rp1) ? sd[li] : 0;
      float2 pv = (li < rp1) ? pk[dv] : make_float2(0.f, 0.f);
      int cl = min(64, rp1 - j0);
      for (int j = 0; j < cl; j++) {
        float dd = __int_as_float(__builtin_amdgcn_readlane(__float_as_int(pv.x), j));
        int b = __builtin_amdgcn_readlane(__float_as_int(pv.y), j);
        atomicAdd(&lds[b * FO + lane], hr * dd);
      }
    }
  }
  __syncthreads();
  for (int i = threadIdx.x; i < NB * FO; i += 512) {
    float v = lds[i];
    if (v != 0.f) atomicAdd(&out_sums[i], v);
  }
}

// ---------------- final: mean + bias ----------------------------------------
__global__ __launch_bounds__(256) void k_final(const float* __restrict__ out_sums,
                                               const float* __restrict__ cnts,
                                               const float* __restrict__ b2,
                                               float* __restrict__ out) {
  int i = blockIdx.x * 256 + threadIdx.x;
  if (i < NB * FO) {
    int b = i >> 6, j = i & 63;
    out[i] = out_sums[i] / fmaxf(cnts[b], 1.0f) + b2[j];
  }
}

extern "C" void kernel_launch(void* const* d_in, const int* in_sizes, int n_in,
                              void* d_out, int out_size, void* d_ws, size_t ws_size,
                              hipStream_t stream) {
  const float* x = (const float*)d_in[0];
  const int* ei = (const int*)d_in[1];     // [2,E] int32
  const int* batch = (const int*)d_in[2];  // [N] int32 (sorted)
  const float* W1 = (const float*)d_in[3];
  const float* b1 = (const float*)d_in[4];
  const float* W2 = (const float*)d_in[5];
  const float* b2 = (const float*)d_in[6];
  float* out = (float*)d_out;

  const int* es = ei;       // src
  const int* ed = ei + NE;  // dst

  // workspace (4B words), all offsets 64-aligned:
  // degi/dinv 100032 | pk 200064 | row_ptr 100032 | cursor 100032 | blk 128 |
  // sd 1600000 | aggx/m/h2 6400000 | h1(bf16) 3200000 w | out_sums 4096 | cnts 64
  char* w = (char*)d_ws;
  int*    degi    = (int*)w;                       w += 100032 * 4;
  float2* pk      = (float2*)w;                    w += 200064 * 4;
  int*    row_ptr = (int*)w;                       w += 100032 * 4;
  int*    cursor  = (int*)w;                       w += 100032 * 4;
  int*    blksum  = (int*)w;                       w += 128 * 4;
  int*    sd      = (int*)w;                       w += (size_t)NE * 4;
  float*  aggx    = (float*)w;                     w += (size_t)NN * FI * 4;  // m -> aggx -> h2
  unsigned* h1b   = (unsigned*)w;                  w += (size_t)NN * (FH / 2) * 4;
  float*  out_sums = (float*)w;                    w += 4096 * 4;
  float*  cnts    = (float*)w;
  float*  dinv = (float*)degi;  // rsqrt written in place over int degree

  k_init<<<391, 256, 0, stream>>>(degi, cursor, out_sums);
  k_deg_hist<<<1024, 256, 0, stream>>>(es, ed, degi, cursor);
  k_dinv_pk<<<391, 256, 0, stream>>>(degi, batch, dinv, pk);
  k_scan1<<<SCAN_BLKS, 1024, 0, stream>>>(cursor, row_ptr, blksum);
  k_scan2<<<1, 128, 0, stream>>>(blksum);
  k_scan3<<<SCAN_BLKS, 1024, 0, stream>>>(row_ptr, blksum, cursor);
  k_place<<<1024, 256, 0, stream>>>(es, ed, cursor, sd);
  k_zero<<<6250, 256, 0, stream>>>((float4*)aggx, NN * FI / 4);
  k_scatter<<<2048, 256, 0, stream>>>(row_ptr, sd, dinv, x, aggx);
  k_aggx_fin<<<6250, 256, 0, stream>>>(x, dinv, aggx);
  k_gemm1<<<(NN + 63) / 64, 256, 0, stream>>>(aggx, W1, b1, h1b);
  k_gemm2<<<(NN + 63) / 64, 256, 0, stream>>>(h1b, W2, aggx);  // h2 -> aggx
  k_cnt_bs<<<1, 128, 0, stream>>>(batch, cnts);
  k_pool<<<1024, 512, 0, stream>>>(row_ptr, sd, pk, aggx, out_sums);
  k_final<<<16, 256, 0, stream>>>(out_sums, cnts, b2, out);
}

// Round 8
// 551.991 us; speedup vs baseline: 2.3855x; 2.3855x over previous
//
#include <hip/hip_runtime.h>

// GCN encoder: 2x GCNConv (symmetric norm, self-loops) + global mean pool.
// N=100000, E=1600000, F_IN=64, H=128, O=64, B=64.
//
// R3: k_cnt atomics -> binary search (-623us, matched).
// R5: 4-edge MLP batching: NULL (-5%). Latency theory falsified.
// R7: src-sorted + sequential reads: FETCH 211->20MB, time UNCHANGED.
//     => the wall was never memory: ~204 cy/edge serialized LDS/global f32
//     atomics (all three variants ~560us).
// R8: dst-sorted edges; per-dst register accumulation, PLAIN STORES.
//     Pool = segmented sum over sorted batch (flush-on-boundary, ~8K LDS
//     atomics total instead of 109M). No per-edge atomics anywhere.

#define NN 100000
#define NE 1600000
#define FI 64
#define FH 128
#define FO 64
#define NB 64
#define SCAN_BLKS 98  // ceil(100000/1024)

// ---------------- init: zero int-degree, pooled sums ------------------------
__global__ __launch_bounds__(256) void k_init(int* __restrict__ degi,
                                              float* __restrict__ out_sums) {
  int i = blockIdx.x * 256 + threadIdx.x;
  if (i < NN) degi[i] = 0;
  if (i < NB * FO) out_sums[i] = 0.0f;
}

// ---------------- in-degree over dst (= sort histogram) ---------------------
__global__ __launch_bounds__(256) void k_deg(const int* __restrict__ ed,
                                             int* __restrict__ degi) {
  int stride = gridDim.x * 256;
  for (int e = blockIdx.x * 256 + threadIdx.x; e < NE; e += stride)
    atomicAdd(&degi[ed[e]], 1);
}

// ---------------- dinv = rsqrt(1+indeg) (degi preserved for scan) -----------
__global__ __launch_bounds__(256) void k_dinv(const int* __restrict__ degi,
                                              float* __restrict__ dinv) {
  int i = blockIdx.x * 256 + threadIdx.x;
  if (i < NN) dinv[i] = rsqrtf(1.0f + (float)degi[i]);
}

// ---------------- exclusive scan of degi -> row_ptr, cursor ------------------
__global__ __launch_bounds__(1024) void k_scan1(const int* __restrict__ hist,
                                                int* __restrict__ row_ptr,
                                                int* __restrict__ blksum) {
  __shared__ int s[1024];
  int tid = threadIdx.x;
  int i = blockIdx.x * 1024 + tid;
  int v = (i < NN) ? hist[i] : 0;
  s[tid] = v;
  __syncthreads();
  for (int off = 1; off < 1024; off <<= 1) {
    int t = (tid >= off) ? s[tid - off] : 0;
    __syncthreads();
    s[tid] += t;
    __syncthreads();
  }
  if (i < NN) row_ptr[i] = s[tid] - v;  // exclusive, pre-block-offset
  if (tid == 1023) blksum[blockIdx.x] = s[1023];
}

__global__ __launch_bounds__(128) void k_scan2(int* __restrict__ blksum) {
  if (threadIdx.x == 0) {
    int run = 0;
    for (int i = 0; i < SCAN_BLKS; i++) { int t = blksum[i]; blksum[i] = run; run += t; }
  }
}

__global__ __launch_bounds__(1024) void k_scan3(int* __restrict__ row_ptr,
                                                const int* __restrict__ blksum,
                                                int* __restrict__ cursor) {
  int i = blockIdx.x * 1024 + threadIdx.x;
  if (i < NN) {
    int rp = row_ptr[i] + blksum[blockIdx.x];
    row_ptr[i] = rp;
    cursor[i] = rp;
  }
  if (i == 0) row_ptr[NN] = NE;
}

// ---------------- placement: ew[pos] = {src, dinv[src]} grouped by dst -------
__global__ __launch_bounds__(256) void k_place(const int* __restrict__ es,
                                               const int* __restrict__ ed,
                                               const float* __restrict__ dinv,
                                               int* __restrict__ cursor,
                                               float2* __restrict__ ew) {
  int stride = gridDim.x * 256;
  for (int e = blockIdx.x * 256 + threadIdx.x; e < NE; e += stride) {
    int d = ed[e];
    int s = es[e];
    int pos = atomicAdd(&cursor[d], 1);
    ew[pos] = make_float2(__int_as_float(s), dinv[s]);
  }
}

// ---------------- pass1: aggx[d] = dinv_d*(dinv_d*x[d] + sum w*x[s]) ---------
// wave per dst row; register accumulation; 4-unrolled independent gathers;
// plain store. NO atomics.
__global__ __launch_bounds__(256) void k_agg1(const int* __restrict__ row_ptr,
                                              const float2* __restrict__ ew,
                                              const float* __restrict__ dinv,
                                              const float* __restrict__ x,
                                              float* __restrict__ aggx) {
  int lane = threadIdx.x & 63;
  int wid = (blockIdx.x * 256 + threadIdx.x) >> 6;
  int nw = (gridDim.x * 256) >> 6;
  for (int d = wid; d < NN; d += nw) {
    float dd = dinv[d];
    float acc = dd * x[(size_t)d * FI + lane];  // self-loop (x dd at store)
    int rp0 = row_ptr[d], rp1 = row_ptr[d + 1];
    int j = rp0;
    for (; j + 4 <= rp1; j += 4) {
      float2 e0 = ew[j], e1 = ew[j + 1], e2 = ew[j + 2], e3 = ew[j + 3];
      float g0 = x[(size_t)__float_as_int(e0.x) * FI + lane];
      float g1 = x[(size_t)__float_as_int(e1.x) * FI + lane];
      float g2 = x[(size_t)__float_as_int(e2.x) * FI + lane];
      float g3 = x[(size_t)__float_as_int(e3.x) * FI + lane];
      acc += g0 * e0.y;
      acc += g1 * e1.y;
      acc += g2 * e2.y;
      acc += g3 * e3.y;
    }
    for (; j < rp1; j++) {
      float2 e0 = ew[j];
      acc += x[(size_t)__float_as_int(e0.x) * FI + lane] * e0.y;
    }
    aggx[(size_t)d * FI + lane] = dd * acc;
  }
}

// ---------------- bf16 helpers ----------------------------------------------
__device__ __forceinline__ unsigned bf16rn(float f) {
  unsigned u = __float_as_uint(f);
  return (u + 0x7fffu + ((u >> 16) & 1u)) >> 16;
}
__device__ __forceinline__ float bf16lo(unsigned u) { return __uint_as_float(u << 16); }
__device__ __forceinline__ float bf16hi(unsigned u) { return __uint_as_float(u & 0xffff0000u); }

// ---------------- GEMM1: h1 = relu(aggx @ W1 + b1) -> bf16 ------------------
__global__ __launch_bounds__(256) void k_gemm1(const float* __restrict__ X,
                                               const float* __restrict__ W,
                                               const float* __restrict__ bias,
                                               unsigned* __restrict__ Y) {  // bf16 pairs
  __shared__ float XsT[FI][64];
  __shared__ float Ws[FI][FH];
  int tid = threadIdx.x;
  int row0 = blockIdx.x * 64;

  for (int i = tid; i < FI * FH / 4; i += 256)
    ((float4*)&Ws[0][0])[i] = ((const float4*)W)[i];

  for (int i = tid; i < 64 * (FI / 4); i += 256) {
    int c4 = i & 15;
    int r = i >> 4;
    int row = row0 + r;
    float4 v = (row < NN) ? ((const float4*)X)[row * (FI / 4) + c4]
                          : make_float4(0.f, 0.f, 0.f, 0.f);
    XsT[c4 * 4 + 0][r] = v.x; XsT[c4 * 4 + 1][r] = v.y;
    XsT[c4 * 4 + 2][r] = v.z; XsT[c4 * 4 + 3][r] = v.w;
  }
  __syncthreads();

  int tr = tid & 15, tc = tid >> 4;
  float acc[4][8];
#pragma unroll
  for (int i = 0; i < 4; i++)
#pragma unroll
    for (int j = 0; j < 8; j++) acc[i][j] = 0.f;

#pragma unroll 8
  for (int k = 0; k < FI; k++) {
    float4 a = *(const float4*)&XsT[k][tr * 4];
    float4 w0 = *(const float4*)&Ws[k][tc * 8];
    float4 w1 = *(const float4*)&Ws[k][tc * 8 + 4];
    float av[4] = {a.x, a.y, a.z, a.w};
    float wv[8] = {w0.x, w0.y, w0.z, w0.w, w1.x, w1.y, w1.z, w1.w};
#pragma unroll
    for (int i = 0; i < 4; i++)
#pragma unroll
      for (int j = 0; j < 8; j++) acc[i][j] += av[i] * wv[j];
  }

  float4 bv0 = *(const float4*)&bias[tc * 8];
  float4 bv1 = *(const float4*)&bias[tc * 8 + 4];
  float bb[8] = {bv0.x, bv0.y, bv0.z, bv0.w, bv1.x, bv1.y, bv1.z, bv1.w};
#pragma unroll
  for (int i = 0; i < 4; i++) {
    int row = row0 + tr * 4 + i;
    if (row < NN) {
      unsigned o[4];
#pragma unroll
      for (int j = 0; j < 4; j++) {
        float v0 = acc[i][2 * j] + bb[2 * j];
        float v1 = acc[i][2 * j + 1] + bb[2 * j + 1];
        v0 = v0 > 0.f ? v0 : 0.f;
        v1 = v1 > 0.f ? v1 : 0.f;
        o[j] = bf16rn(v0) | (bf16rn(v1) << 16);
      }
      *(uint4*)&Y[(size_t)row * 64 + tc * 4] = make_uint4(o[0], o[1], o[2], o[3]);
    }
  }
}

// ---------------- GEMM2: h2 = h1(bf16) @ W2 ---------------------------------
__global__ __launch_bounds__(256) void k_gemm2(const unsigned* __restrict__ Xb,
                                               const float* __restrict__ W,
                                               float* __restrict__ Y) {
  __shared__ float XsT[FH][64];
  __shared__ float Ws[FH][FO];
  int tid = threadIdx.x;
  int row0 = blockIdx.x * 64;

  for (int i = tid; i < FH * FO / 4; i += 256)
    ((float4*)&Ws[0][0])[i] = ((const float4*)W)[i];

  for (int i = tid; i < 64 * (FH / 8); i += 256) {
    int c8 = (i & 15) * 8;
    int r = i >> 4;
    int row = row0 + r;
    uint4 q = (row < NN) ? *(const uint4*)&Xb[(size_t)row * 64 + (c8 >> 1)]
                         : make_uint4(0, 0, 0, 0);
    XsT[c8 + 0][r] = bf16lo(q.x); XsT[c8 + 1][r] = bf16hi(q.x);
    XsT[c8 + 2][r] = bf16lo(q.y); XsT[c8 + 3][r] = bf16hi(q.y);
    XsT[c8 + 4][r] = bf16lo(q.z); XsT[c8 + 5][r] = bf16hi(q.z);
    XsT[c8 + 6][r] = bf16lo(q.w); XsT[c8 + 7][r] = bf16hi(q.w);
  }
  __syncthreads();

  int tr = tid & 15, tc = tid >> 4;
  float acc[4][4];
#pragma unroll
  for (int i = 0; i < 4; i++)
#pragma unroll
    for (int j = 0; j < 4; j++) acc[i][j] = 0.f;

#pragma unroll 8
  for (int k = 0; k < FH; k++) {
    float4 a = *(const float4*)&XsT[k][tr * 4];
    float4 w = *(const float4*)&Ws[k][tc * 4];
    float av[4] = {a.x, a.y, a.z, a.w};
    float wv[4] = {w.x, w.y, w.z, w.w};
#pragma unroll
    for (int i = 0; i < 4; i++)
#pragma unroll
      for (int j = 0; j < 4; j++) acc[i][j] += av[i] * wv[j];
  }

#pragma unroll
  for (int i = 0; i < 4; i++) {
    int row = row0 + tr * 4 + i;
    if (row < NN)
      *(float4*)&Y[(size_t)row * FO + tc * 4] =
          make_float4(acc[i][0], acc[i][1], acc[i][2], acc[i][3]);
  }
}

// ---------------- node counts per graph: binary search on SORTED batch ------
__global__ __launch_bounds__(128) void k_cnt_bs(const int* __restrict__ batch,
                                                float* __restrict__ cnts) {
  __shared__ int lb[NB + 1];
  int b = threadIdx.x;
  if (b <= NB) {
    int lo = 0, hi = NN;
    while (lo < hi) {
      int mid = (lo + hi) >> 1;
      if (batch[mid] < b) lo = mid + 1; else hi = mid;
    }
    lb[b] = lo;
  }
  __syncthreads();
  if (b < NB) cnts[b] = (float)(lb[b + 1] - lb[b]);
}

// ---------------- pass2 + pool: segmented sum over sorted batch -------------
// wave handles a CONTIGUOUS node chunk; per node: register-accumulated
// layer-2 row (same gather structure as k_agg1 on h2); run-accumulator per
// graph flushed to LDS only on boundary/end (~2 LDS atomics per wave).
__global__ __launch_bounds__(256) void k_agg2pool(const int* __restrict__ row_ptr,
                                                  const float2* __restrict__ ew,
                                                  const float* __restrict__ dinv,
                                                  const int* __restrict__ batch,
                                                  const float* __restrict__ h2,
                                                  float* __restrict__ out_sums) {
  __shared__ float lds[NB * FO];  // 16KB
  for (int i = threadIdx.x; i < NB * FO; i += 256) lds[i] = 0.f;
  __syncthreads();

  int lane = threadIdx.x & 63;
  int gw = (blockIdx.x * 256 + threadIdx.x) >> 6;  // global wave
  int ngw = (gridDim.x * 256) >> 6;
  int chunk = (NN + ngw - 1) / ngw;
  int n0 = gw * chunk;
  int n1 = min(NN, n0 + chunk);

  int bcur = -1;
  float acc = 0.f;
  for (int d = n0; d < n1; d++) {
    int b = batch[d];
    if (b != bcur) {
      if (bcur >= 0) atomicAdd(&lds[bcur * FO + lane], acc);
      bcur = b;
      acc = 0.f;
    }
    float dd = dinv[d];
    float a = dd * h2[(size_t)d * FO + lane];  // self-loop (x dd below)
    int rp0 = row_ptr[d], rp1 = row_ptr[d + 1];
    int j = rp0;
    for (; j + 4 <= rp1; j += 4) {
      float2 e0 = ew[j], e1 = ew[j + 1], e2 = ew[j + 2], e3 = ew[j + 3];
      float g0 = h2[(size_t)__float_as_int(e0.x) * FO + lane];
      float g1 = h2[(size_t)__float_as_int(e1.x) * FO + lane];
      float g2 = h2[(size_t)__float_as_int(e2.x) * FO + lane];
      float g3 = h2[(size_t)__float_as_int(e3.x) * FO + lane];
      a += g0 * e0.y;
      a += g1 * e1.y;
      a += g2 * e2.y;
      a += g3 * e3.y;
    }
    for (; j < rp1; j++) {
      float2 e0 = ew[j];
      a += h2[(size_t)__float_as_int(e0.x) * FO + lane] * e0.y;
    }
    acc += dd * a;
  }
  if (bcur >= 0) atomicAdd(&lds[bcur * FO + lane], acc);

  __syncthreads();
  for (int i = threadIdx.x; i < NB * FO; i += 256) {
    float v = lds[i];
    if (v != 0.f) atomicAdd(&out_sums[i], v);
  }
}

// ---------------- final: mean + bias ----------------------------------------
__global__ __launch_bounds__(256) void k_final(const float* __restrict__ out_sums,
                                               const float* __restrict__ cnts,
                                               const float* __restrict__ b2,
                                               float* __restrict__ out) {
  int i = blockIdx.x * 256 + threadIdx.x;
  if (i < NB * FO) {
    int b = i >> 6, j = i & 63;
    out[i] = out_sums[i] / fmaxf(cnts[b], 1.0f) + b2[j];
  }
}

extern "C" void kernel_launch(void* const* d_in, const int* in_sizes, int n_in,
                              void* d_out, int out_size, void* d_ws, size_t ws_size,
                              hipStream_t stream) {
  const float* x = (const float*)d_in[0];
  const int* ei = (const int*)d_in[1];     // [2,E] int32
  const int* batch = (const int*)d_in[2];  // [N] int32 (sorted)
  const float* W1 = (const float*)d_in[3];
  const float* b1 = (const float*)d_in[4];
  const float* W2 = (const float*)d_in[5];
  const float* b2 = (const float*)d_in[6];
  float* out = (float*)d_out;

  const int* es = ei;       // src
  const int* ed = ei + NE;  // dst

  // workspace (4B words): degi 100032 | dinv 100032 | row_ptr 100032 |
  // cursor 100032 | blksum 128 | ew 3.2M | aggx/h2 6.4M | h1b 3.2M |
  // out_sums 4096 | cnts 64   => ~52.9 MB total
  char* w = (char*)d_ws;
  int*    degi    = (int*)w;       w += 100032 * 4;
  float*  dinv    = (float*)w;     w += 100032 * 4;
  int*    row_ptr = (int*)w;       w += 100032 * 4;
  int*    cursor  = (int*)w;       w += 100032 * 4;
  int*    blksum  = (int*)w;       w += 128 * 4;
  float2* ew      = (float2*)w;    w += (size_t)NE * 8;
  float*  aggx    = (float*)w;     w += (size_t)NN * FI * 4;  // aggx -> h2
  unsigned* h1b   = (unsigned*)w;  w += (size_t)NN * (FH / 2) * 4;
  float*  out_sums = (float*)w;    w += 4096 * 4;
  float*  cnts    = (float*)w;

  k_init<<<391, 256, 0, stream>>>(degi, out_sums);
  k_deg<<<1024, 256, 0, stream>>>(ed, degi);
  k_dinv<<<391, 256, 0, stream>>>(degi, dinv);
  k_scan1<<<SCAN_BLKS, 1024, 0, stream>>>(degi, row_ptr, blksum);
  k_scan2<<<1, 128, 0, stream>>>(blksum);
  k_scan3<<<SCAN_BLKS, 1024, 0, stream>>>(row_ptr, blksum, cursor);
  k_place<<<1024, 256, 0, stream>>>(es, ed, dinv, cursor, ew);
  k_agg1<<<1024, 256, 0, stream>>>(row_ptr, ew, dinv, x, aggx);
  k_gemm1<<<(NN + 63) / 64, 256, 0, stream>>>(aggx, W1, b1, h1b);
  k_gemm2<<<(NN + 63) / 64, 256, 0, stream>>>(h1b, W2, aggx);  // h2 -> aggx
  k_cnt_bs<<<1, 128, 0, stream>>>(batch, cnts);
  k_agg2pool<<<1024, 256, 0, stream>>>(row_ptr, ew, dinv, batch, aggx, out_sums);
  k_final<<<16, 256, 0, stream>>>(out_sums, cnts, b2, out);
}

// Round 10
// 545.950 us; speedup vs baseline: 2.4119x; 1.0111x over previous
//
#include <hip/hip_runtime.h>

// GCN encoder: 2x GCNConv (symmetric norm, self-loops) + global mean pool.
// N=100000, E=1600000, F_IN=64, H=128, O=64, B=64.
//
// R3: k_cnt atomics -> binary search (-623us, matched).
// R5: 4-edge MLP batching: NULL (-5%). Latency theory falsified.
// R7: src-sorted sequential reads: FETCH 211->20MB, time UNCHANGED => wall
//     was per-edge atomics (~50+ns serialized wave-wide RMW), not memory.
// R8: dst-sorted + register accumulation + plain stores: 1317 -> 552us.
// R9: k_agg1/k_agg2pool are fetch-throughput-bound on random 256B row
//     gathers (dur ~= FETCH / 1.6 TB/s). Halve the rows: gather x and h2
//     as bf16 (128B rows). k_xbf16 converts x once (~7us).

#define NN 100000
#define NE 1600000
#define FI 64
#define FH 128
#define FO 64
#define NB 64
#define SCAN_BLKS 98  // ceil(100000/1024)

// ---------------- bf16 helpers ----------------------------------------------
__device__ __forceinline__ unsigned bf16rn(float f) {
  unsigned u = __float_as_uint(f);
  return (u + 0x7fffu + ((u >> 16) & 1u)) >> 16;
}
__device__ __forceinline__ float bf16lo(unsigned u) { return __uint_as_float(u << 16); }
__device__ __forceinline__ float bf16hi(unsigned u) { return __uint_as_float(u & 0xffff0000u); }
__device__ __forceinline__ float bf16f(unsigned short u) {
  return __uint_as_float((unsigned)u << 16);
}

// ---------------- init: zero int-degree, pooled sums ------------------------
__global__ __launch_bounds__(256) void k_init(int* __restrict__ degi,
                                              float* __restrict__ out_sums) {
  int i = blockIdx.x * 256 + threadIdx.x;
  if (i < NN) degi[i] = 0;
  if (i < NB * FO) out_sums[i] = 0.0f;
}

// ---------------- in-degree over dst (= sort histogram) ---------------------
__global__ __launch_bounds__(256) void k_deg(const int* __restrict__ ed,
                                             int* __restrict__ degi) {
  int stride = gridDim.x * 256;
  for (int e = blockIdx.x * 256 + threadIdx.x; e < NE; e += stride)
    atomicAdd(&degi[ed[e]], 1);
}

// ---------------- dinv = rsqrt(1+indeg) (degi preserved for scan) -----------
__global__ __launch_bounds__(256) void k_dinv(const int* __restrict__ degi,
                                              float* __restrict__ dinv) {
  int i = blockIdx.x * 256 + threadIdx.x;
  if (i < NN) dinv[i] = rsqrtf(1.0f + (float)degi[i]);
}

// ---------------- x -> bf16 (halves gather traffic in k_agg1) ---------------
__global__ __launch_bounds__(256) void k_xbf16(const float* __restrict__ x,
                                               unsigned* __restrict__ xb) {  // bf16 pairs
  int i = blockIdx.x * 256 + threadIdx.x;  // 8 elems per thread
  if (i < NN * FI / 8) {
    float4 v0 = ((const float4*)x)[2 * i];
    float4 v1 = ((const float4*)x)[2 * i + 1];
    uint4 q;
    q.x = bf16rn(v0.x) | (bf16rn(v0.y) << 16);
    q.y = bf16rn(v0.z) | (bf16rn(v0.w) << 16);
    q.z = bf16rn(v1.x) | (bf16rn(v1.y) << 16);
    q.w = bf16rn(v1.z) | (bf16rn(v1.w) << 16);
    ((uint4*)xb)[i] = q;
  }
}

// ---------------- exclusive scan of degi -> row_ptr, cursor ------------------
__global__ __launch_bounds__(1024) void k_scan1(const int* __restrict__ hist,
                                                int* __restrict__ row_ptr,
                                                int* __restrict__ blksum) {
  __shared__ int s[1024];
  int tid = threadIdx.x;
  int i = blockIdx.x * 1024 + tid;
  int v = (i < NN) ? hist[i] : 0;
  s[tid] = v;
  __syncthreads();
  for (int off = 1; off < 1024; off <<= 1) {
    int t = (tid >= off) ? s[tid - off] : 0;
    __syncthreads();
    s[tid] += t;
    __syncthreads();
  }
  if (i < NN) row_ptr[i] = s[tid] - v;
  if (tid == 1023) blksum[blockIdx.x] = s[1023];
}

__global__ __launch_bounds__(128) void k_scan2(int* __restrict__ blksum) {
  if (threadIdx.x == 0) {
    int run = 0;
    for (int i = 0; i < SCAN_BLKS; i++) { int t = blksum[i]; blksum[i] = run; run += t; }
  }
}

__global__ __launch_bounds__(1024) void k_scan3(int* __restrict__ row_ptr,
                                                const int* __restrict__ blksum,
                                                int* __restrict__ cursor) {
  int i = blockIdx.x * 1024 + threadIdx.x;
  if (i < NN) {
    int rp = row_ptr[i] + blksum[blockIdx.x];
    row_ptr[i] = rp;
    cursor[i] = rp;
  }
  if (i == 0) row_ptr[NN] = NE;
}

// ---------------- placement: ew[pos] = {src, dinv[src]} grouped by dst -------
__global__ __launch_bounds__(256) void k_place(const int* __restrict__ es,
                                               const int* __restrict__ ed,
                                               const float* __restrict__ dinv,
                                               int* __restrict__ cursor,
                                               float2* __restrict__ ew) {
  int stride = gridDim.x * 256;
  for (int e = blockIdx.x * 256 + threadIdx.x; e < NE; e += stride) {
    int d = ed[e];
    int s = es[e];
    int pos = atomicAdd(&cursor[d], 1);
    ew[pos] = make_float2(__int_as_float(s), dinv[s]);
  }
}

// ---------------- pass1: aggx[d] = dinv_d*(dinv_d*x[d] + sum w*x[s]) ---------
// wave per dst row; register accumulation; bf16 x gathers (128B rows).
__global__ __launch_bounds__(256) void k_agg1(const int* __restrict__ row_ptr,
                                              const float2* __restrict__ ew,
                                              const float* __restrict__ dinv,
                                              const unsigned short* __restrict__ xb,
                                              float* __restrict__ aggx) {
  int lane = threadIdx.x & 63;
  int wid = (blockIdx.x * 256 + threadIdx.x) >> 6;
  int nw = (gridDim.x * 256) >> 6;
  for (int d = wid; d < NN; d += nw) {
    float dd = dinv[d];
    float acc = dd * bf16f(xb[(size_t)d * FI + lane]);  // self-loop
    int rp0 = row_ptr[d], rp1 = row_ptr[d + 1];
    int j = rp0;
    for (; j + 4 <= rp1; j += 4) {
      float2 e0 = ew[j], e1 = ew[j + 1], e2 = ew[j + 2], e3 = ew[j + 3];
      float g0 = bf16f(xb[(size_t)__float_as_int(e0.x) * FI + lane]);
      float g1 = bf16f(xb[(size_t)__float_as_int(e1.x) * FI + lane]);
      float g2 = bf16f(xb[(size_t)__float_as_int(e2.x) * FI + lane]);
      float g3 = bf16f(xb[(size_t)__float_as_int(e3.x) * FI + lane]);
      acc += g0 * e0.y;
      acc += g1 * e1.y;
      acc += g2 * e2.y;
      acc += g3 * e3.y;
    }
    for (; j < rp1; j++) {
      float2 e0 = ew[j];
      acc += bf16f(xb[(size_t)__float_as_int(e0.x) * FI + lane]) * e0.y;
    }
    aggx[(size_t)d * FI + lane] = dd * acc;
  }
}

// ---------------- GEMM1: h1 = relu(aggx @ W1 + b1) -> bf16 ------------------
__global__ __launch_bounds__(256) void k_gemm1(const float* __restrict__ X,
                                               const float* __restrict__ W,
                                               const float* __restrict__ bias,
                                               unsigned* __restrict__ Y) {  // bf16 pairs
  __shared__ float XsT[FI][64];
  __shared__ float Ws[FI][FH];
  int tid = threadIdx.x;
  int row0 = blockIdx.x * 64;

  for (int i = tid; i < FI * FH / 4; i += 256)
    ((float4*)&Ws[0][0])[i] = ((const float4*)W)[i];

  for (int i = tid; i < 64 * (FI / 4); i += 256) {
    int c4 = i & 15;
    int r = i >> 4;
    int row = row0 + r;
    float4 v = (row < NN) ? ((const float4*)X)[row * (FI / 4) + c4]
                          : make_float4(0.f, 0.f, 0.f, 0.f);
    XsT[c4 * 4 + 0][r] = v.x; XsT[c4 * 4 + 1][r] = v.y;
    XsT[c4 * 4 + 2][r] = v.z; XsT[c4 * 4 + 3][r] = v.w;
  }
  __syncthreads();

  int tr = tid & 15, tc = tid >> 4;
  float acc[4][8];
#pragma unroll
  for (int i = 0; i < 4; i++)
#pragma unroll
    for (int j = 0; j < 8; j++) acc[i][j] = 0.f;

#pragma unroll 8
  for (int k = 0; k < FI; k++) {
    float4 a = *(const float4*)&XsT[k][tr * 4];
    float4 w0 = *(const float4*)&Ws[k][tc * 8];
    float4 w1 = *(const float4*)&Ws[k][tc * 8 + 4];
    float av[4] = {a.x, a.y, a.z, a.w};
    float wv[8] = {w0.x, w0.y, w0.z, w0.w, w1.x, w1.y, w1.z, w1.w};
#pragma unroll
    for (int i = 0; i < 4; i++)
#pragma unroll
      for (int j = 0; j < 8; j++) acc[i][j] += av[i] * wv[j];
  }

  float4 bv0 = *(const float4*)&bias[tc * 8];
  float4 bv1 = *(const float4*)&bias[tc * 8 + 4];
  float bb[8] = {bv0.x, bv0.y, bv0.z, bv0.w, bv1.x, bv1.y, bv1.z, bv1.w};
#pragma unroll
  for (int i = 0; i < 4; i++) {
    int row = row0 + tr * 4 + i;
    if (row < NN) {
      unsigned o[4];
#pragma unroll
      for (int j = 0; j < 4; j++) {
        float v0 = acc[i][2 * j] + bb[2 * j];
        float v1 = acc[i][2 * j + 1] + bb[2 * j + 1];
        v0 = v0 > 0.f ? v0 : 0.f;
        v1 = v1 > 0.f ? v1 : 0.f;
        o[j] = bf16rn(v0) | (bf16rn(v1) << 16);
      }
      *(uint4*)&Y[(size_t)row * 64 + tc * 4] = make_uint4(o[0], o[1], o[2], o[3]);
    }
  }
}

// ---------------- GEMM2: h2 = h1(bf16) @ W2 -> bf16 -------------------------
__global__ __launch_bounds__(256) void k_gemm2(const unsigned* __restrict__ Xb,
                                               const float* __restrict__ W,
                                               unsigned* __restrict__ Yb) {  // bf16 pairs
  __shared__ float XsT[FH][64];
  __shared__ float Ws[FH][FO];
  int tid = threadIdx.x;
  int row0 = blockIdx.x * 64;

  for (int i = tid; i < FH * FO / 4; i += 256)
    ((float4*)&Ws[0][0])[i] = ((const float4*)W)[i];

  for (int i = tid; i < 64 * (FH / 8); i += 256) {
    int c8 = (i & 15) * 8;
    int r = i >> 4;
    int row = row0 + r;
    uint4 q = (row < NN) ? *(const uint4*)&Xb[(size_t)row * 64 + (c8 >> 1)]
                         : make_uint4(0, 0, 0, 0);
    XsT[c8 + 0][r] = bf16lo(q.x); XsT[c8 + 1][r] = bf16hi(q.x);
    XsT[c8 + 2][r] = bf16lo(q.y); XsT[c8 + 3][r] = bf16hi(q.y);
    XsT[c8 + 4][r] = bf16lo(q.z); XsT[c8 + 5][r] = bf16hi(q.z);
    XsT[c8 + 6][r] = bf16lo(q.w); XsT[c8 + 7][r] = bf16hi(q.w);
  }
  __syncthreads();

  int tr = tid & 15, tc = tid >> 4;
  float acc[4][4];
#pragma unroll
  for (int i = 0; i < 4; i++)
#pragma unroll
    for (int j = 0; j < 4; j++) acc[i][j] = 0.f;

#pragma unroll 8
  for (int k = 0; k < FH; k++) {
    float4 a = *(const float4*)&XsT[k][tr * 4];
    float4 w = *(const float4*)&Ws[k][tc * 4];
    float av[4] = {a.x, a.y, a.z, a.w};
    float wv[4] = {w.x, w.y, w.z, w.w};
#pragma unroll
    for (int i = 0; i < 4; i++)
#pragma unroll
      for (int j = 0; j < 4; j++) acc[i][j] += av[i] * wv[j];
  }

#pragma unroll
  for (int i = 0; i < 4; i++) {
    int row = row0 + tr * 4 + i;
    if (row < NN) {
      uint2 o;
      o.x = bf16rn(acc[i][0]) | (bf16rn(acc[i][1]) << 16);
      o.y = bf16rn(acc[i][2]) | (bf16rn(acc[i][3]) << 16);
      *(uint2*)&Yb[(size_t)row * 32 + tc * 2] = o;
    }
  }
}

// ---------------- node counts per graph: binary search on SORTED batch ------
__global__ __launch_bounds__(128) void k_cnt_bs(const int* __restrict__ batch,
                                                float* __restrict__ cnts) {
  __shared__ int lb[NB + 1];
  int b = threadIdx.x;
  if (b <= NB) {
    int lo = 0, hi = NN;
    while (lo < hi) {
      int mid = (lo + hi) >> 1;
      if (batch[mid] < b) lo = mid + 1; else hi = mid;
    }
    lb[b] = lo;
  }
  __syncthreads();
  if (b < NB) cnts[b] = (float)(lb[b + 1] - lb[b]);
}

// ---------------- pass2 + pool: segmented sum over sorted batch -------------
// bf16 h2 gathers (128B rows); run-accumulator flushed on graph boundary.
__global__ __launch_bounds__(256) void k_agg2pool(const int* __restrict__ row_ptr,
                                                  const float2* __restrict__ ew,
                                                  const float* __restrict__ dinv,
                                                  const int* __restrict__ batch,
                                                  const unsigned short* __restrict__ h2b,
                                                  float* __restrict__ out_sums) {
  __shared__ float lds[NB * FO];  // 16KB
  for (int i = threadIdx.x; i < NB * FO; i += 256) lds[i] = 0.f;
  __syncthreads();

  int lane = threadIdx.x & 63;
  int gw = (blockIdx.x * 256 + threadIdx.x) >> 6;
  int ngw = (gridDim.x * 256) >> 6;
  int chunk = (NN + ngw - 1) / ngw;
  int n0 = gw * chunk;
  int n1 = min(NN, n0 + chunk);

  int bcur = -1;
  float acc = 0.f;
  for (int d = n0; d < n1; d++) {
    int b = batch[d];
    if (b != bcur) {
      if (bcur >= 0) atomicAdd(&lds[bcur * FO + lane], acc);
      bcur = b;
      acc = 0.f;
    }
    float dd = dinv[d];
    float a = dd * bf16f(h2b[(size_t)d * FO + lane]);  // self-loop
    int rp0 = row_ptr[d], rp1 = row_ptr[d + 1];
    int j = rp0;
    for (; j + 4 <= rp1; j += 4) {
      float2 e0 = ew[j], e1 = ew[j + 1], e2 = ew[j + 2], e3 = ew[j + 3];
      float g0 = bf16f(h2b[(size_t)__float_as_int(e0.x) * FO + lane]);
      float g1 = bf16f(h2b[(size_t)__float_as_int(e1.x) * FO + lane]);
      float g2 = bf16f(h2b[(size_t)__float_as_int(e2.x) * FO + lane]);
      float g3 = bf16f(h2b[(size_t)__float_as_int(e3.x) * FO + lane]);
      a += g0 * e0.y;
      a += g1 * e1.y;
      a += g2 * e2.y;
      a += g3 * e3.y;
    }
    for (; j < rp1; j++) {
      float2 e0 = ew[j];
      a += bf16f(h2b[(size_t)__float_as_int(e0.x) * FO + lane]) * e0.y;
    }
    acc += dd * a;
  }
  if (bcur >= 0) atomicAdd(&lds[bcur * FO + lane], acc);

  __syncthreads();
  for (int i = threadIdx.x; i < NB * FO; i += 256) {
    float v = lds[i];
    if (v != 0.f) atomicAdd(&out_sums[i], v);
  }
}

// ---------------- final: mean + bias ----------------------------------------
__global__ __launch_bounds__(256) void k_final(const float* __restrict__ out_sums,
                                               const float* __restrict__ cnts,
                                               const float* __restrict__ b2,
                                               float* __restrict__ out) {
  int i = blockIdx.x * 256 + threadIdx.x;
  if (i < NB * FO) {
    int b = i >> 6, j = i & 63;
    out[i] = out_sums[i] / fmaxf(cnts[b], 1.0f) + b2[j];
  }
}

extern "C" void kernel_launch(void* const* d_in, const int* in_sizes, int n_in,
                              void* d_out, int out_size, void* d_ws, size_t ws_size,
                              hipStream_t stream) {
  const float* x = (const float*)d_in[0];
  const int* ei = (const int*)d_in[1];     // [2,E] int32
  const int* batch = (const int*)d_in[2];  // [N] int32 (sorted)
  const float* W1 = (const float*)d_in[3];
  const float* b1 = (const float*)d_in[4];
  const float* W2 = (const float*)d_in[5];
  const float* b2 = (const float*)d_in[6];
  float* out = (float*)d_out;

  const int* es = ei;       // src
  const int* ed = ei + NE;  // dst

  // workspace (bytes): degi 0.4M | dinv 0.4M | row_ptr 0.4M | cursor 0.4M |
  // blksum | ew 12.8M | xb 12.8M | aggx 25.6M (reused as h2b) | h1b 25.6M |
  // out_sums | cnts  => ~77.5 MB
  char* w = (char*)d_ws;
  int*    degi    = (int*)w;       w += 100032 * 4;
  float*  dinv    = (float*)w;     w += 100032 * 4;
  int*    row_ptr = (int*)w;       w += 100032 * 4;
  int*    cursor  = (int*)w;       w += 100032 * 4;
  int*    blksum  = (int*)w;       w += 128 * 4;
  float2* ew      = (float2*)w;    w += (size_t)NE * 8;
  unsigned* xb    = (unsigned*)w;  w += (size_t)100032 * FI * 2;
  float*  aggx    = (float*)w;     w += (size_t)100032 * FI * 4;
  unsigned* h1b   = (unsigned*)w;  w += (size_t)100032 * (FH / 2) * 4;
  float*  out_sums = (float*)w;    w += 4096 * 4;
  float*  cnts    = (float*)w;
  unsigned* h2b = (unsigned*)aggx;  // aggx dead after gemm1; gemm2 writes h2 bf16 here

  k_init<<<391, 256, 0, stream>>>(degi, out_sums);
  k_deg<<<1024, 256, 0, stream>>>(ed, degi);
  k_dinv<<<391, 256, 0, stream>>>(degi, dinv);
  k_xbf16<<<3125, 256, 0, stream>>>(x, xb);
  k_scan1<<<SCAN_BLKS, 1024, 0, stream>>>(degi, row_ptr, blksum);
  k_scan2<<<1, 128, 0, stream>>>(blksum);
  k_scan3<<<SCAN_BLKS, 1024, 0, stream>>>(row_ptr, blksum, cursor);
  k_place<<<1024, 256, 0, stream>>>(es, ed, dinv, cursor, ew);
  k_agg1<<<1024, 256, 0, stream>>>(row_ptr, ew, dinv, (const unsigned short*)xb, aggx);
  k_gemm1<<<(NN + 63) / 64, 256, 0, stream>>>(aggx, W1, b1, h1b);
  k_gemm2<<<(NN + 63) / 64, 256, 0, stream>>>(h1b, W2, h2b);
  k_cnt_bs<<<1, 128, 0, stream>>>(batch, cnts);
  k_agg2pool<<<1024, 256, 0, stream>>>(row_ptr, ew, dinv, batch,
                                       (const unsigned short*)h2b, out_sums);
  k_final<<<16, 256, 0, stream>>>(out_sums, cnts, b2, out);
}

// Round 12
// 460.127 us; speedup vs baseline: 2.8618x; 1.1865x over previous
//
#include <hip/hip_runtime.h>

// GCN encoder: 2x GCNConv (symmetric norm, self-loops) + global mean pool.
// N=100000, E=1600000, F_IN=64, H=128, O=64, B=64.
//
// R3:  k_cnt atomics -> binary search (-623us, matched).
// R5:  4-edge MLP batching: NULL (-5%) while atomics were the wall.
// R7:  src-sorted seq reads: FETCH 211->20MB, time flat => atomic wall.
// R8:  dst-sorted + register accumulation + plain stores: 1317 -> 552us.
// R10: bf16 gather rows: FETCH halved, time ~flat => request-rate-bound
//      (4 gathers in flight/wave, 39% occupancy), not byte-bound.
// R11: fold dinv_src INTO gathered rows (xbs = x*dinv, h2s = h2*dinv):
//      edge payload 8B->4B (k_place line traffic ~halves; pure index sort),
//      agg loops = gather+add only; 8-deep unroll + grid 2048 (32 waves/CU)
//      to raise outstanding requests.

#define NN 100000
#define NE 1600000
#define FI 64
#define FH 128
#define FO 64
#define NB 64
#define SCAN_BLKS 98  // ceil(100000/1024)

// ---------------- bf16 helpers ----------------------------------------------
__device__ __forceinline__ unsigned bf16rn(float f) {
  unsigned u = __float_as_uint(f);
  return (u + 0x7fffu + ((u >> 16) & 1u)) >> 16;
}
__device__ __forceinline__ float bf16lo(unsigned u) { return __uint_as_float(u << 16); }
__device__ __forceinline__ float bf16hi(unsigned u) { return __uint_as_float(u & 0xffff0000u); }
__device__ __forceinline__ float bf16f(unsigned short u) {
  return __uint_as_float((unsigned)u << 16);
}

// ---------------- init: zero int-degree, pooled sums ------------------------
__global__ __launch_bounds__(256) void k_init(int* __restrict__ degi,
                                              float* __restrict__ out_sums) {
  int i = blockIdx.x * 256 + threadIdx.x;
  if (i < NN) degi[i] = 0;
  if (i < NB * FO) out_sums[i] = 0.0f;
}

// ---------------- in-degree over dst (= sort histogram) ---------------------
__global__ __launch_bounds__(256) void k_deg(const int* __restrict__ ed,
                                             int* __restrict__ degi) {
  int stride = gridDim.x * 256;
  for (int e = blockIdx.x * 256 + threadIdx.x; e < NE; e += stride)
    atomicAdd(&degi[ed[e]], 1);
}

// ---------------- dinv = rsqrt(1+indeg) (degi preserved for scan) -----------
__global__ __launch_bounds__(256) void k_dinv(const int* __restrict__ degi,
                                              float* __restrict__ dinv) {
  int i = blockIdx.x * 256 + threadIdx.x;
  if (i < NN) dinv[i] = rsqrtf(1.0f + (float)degi[i]);
}

// ---------------- xbs = bf16(x * dinv_row): dinv_src folded into rows --------
__global__ __launch_bounds__(256) void k_xscale(const float* __restrict__ x,
                                                const float* __restrict__ dinv,
                                                unsigned* __restrict__ xbs) {  // bf16 pairs
  int i = blockIdx.x * 256 + threadIdx.x;  // 8 elems per thread
  if (i < NN * FI / 8) {
    int node = i >> 3;
    float di = dinv[node];
    float4 v0 = ((const float4*)x)[2 * i];
    float4 v1 = ((const float4*)x)[2 * i + 1];
    uint4 q;
    q.x = bf16rn(v0.x * di) | (bf16rn(v0.y * di) << 16);
    q.y = bf16rn(v0.z * di) | (bf16rn(v0.w * di) << 16);
    q.z = bf16rn(v1.x * di) | (bf16rn(v1.y * di) << 16);
    q.w = bf16rn(v1.z * di) | (bf16rn(v1.w * di) << 16);
    ((uint4*)xbs)[i] = q;
  }
}

// ---------------- exclusive scan of degi -> row_ptr, cursor ------------------
__global__ __launch_bounds__(1024) void k_scan1(const int* __restrict__ hist,
                                                int* __restrict__ row_ptr,
                                                int* __restrict__ blksum) {
  __shared__ int s[1024];
  int tid = threadIdx.x;
  int i = blockIdx.x * 1024 + tid;
  int v = (i < NN) ? hist[i] : 0;
  s[tid] = v;
  __syncthreads();
  for (int off = 1; off < 1024; off <<= 1) {
    int t = (tid >= off) ? s[tid - off] : 0;
    __syncthreads();
    s[tid] += t;
    __syncthreads();
  }
  if (i < NN) row_ptr[i] = s[tid] - v;
  if (tid == 1023) blksum[blockIdx.x] = s[1023];
}

__global__ __launch_bounds__(128) void k_scan2(int* __restrict__ blksum) {
  if (threadIdx.x == 0) {
    int run = 0;
    for (int i = 0; i < SCAN_BLKS; i++) { int t = blksum[i]; blksum[i] = run; run += t; }
  }
}

__global__ __launch_bounds__(1024) void k_scan3(int* __restrict__ row_ptr,
                                                const int* __restrict__ blksum,
                                                int* __restrict__ cursor) {
  int i = blockIdx.x * 1024 + threadIdx.x;
  if (i < NN) {
    int rp = row_ptr[i] + blksum[blockIdx.x];
    row_ptr[i] = rp;
    cursor[i] = rp;
  }
  if (i == 0) row_ptr[NN] = NE;
}

// ---------------- placement: sidx[pos] = src, grouped by dst (4B payload) ----
__global__ __launch_bounds__(256) void k_place(const int* __restrict__ es,
                                               const int* __restrict__ ed,
                                               int* __restrict__ cursor,
                                               int* __restrict__ sidx) {
  int stride = gridDim.x * 256;
  for (int e = blockIdx.x * 256 + threadIdx.x; e < NE; e += stride) {
    int d = ed[e];
    int pos = atomicAdd(&cursor[d], 1);
    sidx[pos] = es[e];
  }
}

// ---------------- pass1: aggx[d] = dinv_d*(xbs[d] + sum xbs[s]) --------------
// (xbs rows pre-scaled by dinv_src; self-loop folds in the same way)
// wave per dst row; 8 independent gathers in flight; plain store.
__global__ __launch_bounds__(256) void k_agg1(const int* __restrict__ row_ptr,
                                              const int* __restrict__ sidx,
                                              const float* __restrict__ dinv,
                                              const unsigned short* __restrict__ xbs,
                                              float* __restrict__ aggx) {
  int lane = threadIdx.x & 63;
  int wid = (blockIdx.x * 256 + threadIdx.x) >> 6;
  int nw = (gridDim.x * 256) >> 6;
  for (int dd0 = wid; dd0 < NN; dd0 += nw) {
    int d = __builtin_amdgcn_readfirstlane(dd0);
    float acc = bf16f(xbs[(size_t)d * FI + lane]);  // self-loop (pre-scaled)
    int rp0 = row_ptr[d], rp1 = row_ptr[d + 1];
    int j = rp0;
    for (; j + 8 <= rp1; j += 8) {
      int4 ia = *(const int4*)(sidx + j);
      int4 ib = *(const int4*)(sidx + j + 4);
      float g0 = bf16f(xbs[(size_t)ia.x * FI + lane]);
      float g1 = bf16f(xbs[(size_t)ia.y * FI + lane]);
      float g2 = bf16f(xbs[(size_t)ia.z * FI + lane]);
      float g3 = bf16f(xbs[(size_t)ia.w * FI + lane]);
      float g4 = bf16f(xbs[(size_t)ib.x * FI + lane]);
      float g5 = bf16f(xbs[(size_t)ib.y * FI + lane]);
      float g6 = bf16f(xbs[(size_t)ib.z * FI + lane]);
      float g7 = bf16f(xbs[(size_t)ib.w * FI + lane]);
      acc += ((g0 + g1) + (g2 + g3)) + ((g4 + g5) + (g6 + g7));
    }
    for (; j < rp1; j++)
      acc += bf16f(xbs[(size_t)sidx[j] * FI + lane]);
    aggx[(size_t)d * FI + lane] = dinv[d] * acc;
  }
}

// ---------------- GEMM1: h1 = relu(aggx @ W1 + b1) -> bf16 ------------------
__global__ __launch_bounds__(256) void k_gemm1(const float* __restrict__ X,
                                               const float* __restrict__ W,
                                               const float* __restrict__ bias,
                                               unsigned* __restrict__ Y) {  // bf16 pairs
  __shared__ float XsT[FI][64];
  __shared__ float Ws[FI][FH];
  int tid = threadIdx.x;
  int row0 = blockIdx.x * 64;

  for (int i = tid; i < FI * FH / 4; i += 256)
    ((float4*)&Ws[0][0])[i] = ((const float4*)W)[i];

  for (int i = tid; i < 64 * (FI / 4); i += 256) {
    int c4 = i & 15;
    int r = i >> 4;
    int row = row0 + r;
    float4 v = (row < NN) ? ((const float4*)X)[row * (FI / 4) + c4]
                          : make_float4(0.f, 0.f, 0.f, 0.f);
    XsT[c4 * 4 + 0][r] = v.x; XsT[c4 * 4 + 1][r] = v.y;
    XsT[c4 * 4 + 2][r] = v.z; XsT[c4 * 4 + 3][r] = v.w;
  }
  __syncthreads();

  int tr = tid & 15, tc = tid >> 4;
  float acc[4][8];
#pragma unroll
  for (int i = 0; i < 4; i++)
#pragma unroll
    for (int j = 0; j < 8; j++) acc[i][j] = 0.f;

#pragma unroll 8
  for (int k = 0; k < FI; k++) {
    float4 a = *(const float4*)&XsT[k][tr * 4];
    float4 w0 = *(const float4*)&Ws[k][tc * 8];
    float4 w1 = *(const float4*)&Ws[k][tc * 8 + 4];
    float av[4] = {a.x, a.y, a.z, a.w};
    float wv[8] = {w0.x, w0.y, w0.z, w0.w, w1.x, w1.y, w1.z, w1.w};
#pragma unroll
    for (int i = 0; i < 4; i++)
#pragma unroll
      for (int j = 0; j < 8; j++) acc[i][j] += av[i] * wv[j];
  }

  float4 bv0 = *(const float4*)&bias[tc * 8];
  float4 bv1 = *(const float4*)&bias[tc * 8 + 4];
  float bb[8] = {bv0.x, bv0.y, bv0.z, bv0.w, bv1.x, bv1.y, bv1.z, bv1.w};
#pragma unroll
  for (int i = 0; i < 4; i++) {
    int row = row0 + tr * 4 + i;
    if (row < NN) {
      unsigned o[4];
#pragma unroll
      for (int j = 0; j < 4; j++) {
        float v0 = acc[i][2 * j] + bb[2 * j];
        float v1 = acc[i][2 * j + 1] + bb[2 * j + 1];
        v0 = v0 > 0.f ? v0 : 0.f;
        v1 = v1 > 0.f ? v1 : 0.f;
        o[j] = bf16rn(v0) | (bf16rn(v1) << 16);
      }
      *(uint4*)&Y[(size_t)row * 64 + tc * 4] = make_uint4(o[0], o[1], o[2], o[3]);
    }
  }
}

// ---------------- GEMM2: h2s = (h1(bf16) @ W2) * dinv_row -> bf16 ------------
__global__ __launch_bounds__(256) void k_gemm2(const unsigned* __restrict__ Xb,
                                               const float* __restrict__ W,
                                               const float* __restrict__ dinv,
                                               unsigned* __restrict__ Yb) {  // bf16 pairs
  __shared__ float XsT[FH][64];
  __shared__ float Ws[FH][FO];
  int tid = threadIdx.x;
  int row0 = blockIdx.x * 64;

  for (int i = tid; i < FH * FO / 4; i += 256)
    ((float4*)&Ws[0][0])[i] = ((const float4*)W)[i];

  for (int i = tid; i < 64 * (FH / 8); i += 256) {
    int c8 = (i & 15) * 8;
    int r = i >> 4;
    int row = row0 + r;
    uint4 q = (row < NN) ? *(const uint4*)&Xb[(size_t)row * 64 + (c8 >> 1)]
                         : make_uint4(0, 0, 0, 0);
    XsT[c8 + 0][r] = bf16lo(q.x); XsT[c8 + 1][r] = bf16hi(q.x);
    XsT[c8 + 2][r] = bf16lo(q.y); XsT[c8 + 3][r] = bf16hi(q.y);
    XsT[c8 + 4][r] = bf16lo(q.z); XsT[c8 + 5][r] = bf16hi(q.z);
    XsT[c8 + 6][r] = bf16lo(q.w); XsT[c8 + 7][r] = bf16hi(q.w);
  }
  __syncthreads();

  int tr = tid & 15, tc = tid >> 4;
  float acc[4][4];
#pragma unroll
  for (int i = 0; i < 4; i++)
#pragma unroll
    for (int j = 0; j < 4; j++) acc[i][j] = 0.f;

#pragma unroll 8
  for (int k = 0; k < FH; k++) {
    float4 a = *(const float4*)&XsT[k][tr * 4];
    float4 w = *(const float4*)&Ws[k][tc * 4];
    float av[4] = {a.x, a.y, a.z, a.w};
    float wv[4] = {w.x, w.y, w.z, w.w};
#pragma unroll
    for (int i = 0; i < 4; i++)
#pragma unroll
      for (int j = 0; j < 4; j++) acc[i][j] += av[i] * wv[j];
  }

#pragma unroll
  for (int i = 0; i < 4; i++) {
    int row = row0 + tr * 4 + i;
    if (row < NN) {
      float dd = dinv[row];
      uint2 o;
      o.x = bf16rn(acc[i][0] * dd) | (bf16rn(acc[i][1] * dd) << 16);
      o.y = bf16rn(acc[i][2] * dd) | (bf16rn(acc[i][3] * dd) << 16);
      *(uint2*)&Yb[(size_t)row * 32 + tc * 2] = o;
    }
  }
}

// ---------------- node counts per graph: binary search on SORTED batch ------
__global__ __launch_bounds__(128) void k_cnt_bs(const int* __restrict__ batch,
                                                float* __restrict__ cnts) {
  __shared__ int lb[NB + 1];
  int b = threadIdx.x;
  if (b <= NB) {
    int lo = 0, hi = NN;
    while (lo < hi) {
      int mid = (lo + hi) >> 1;
      if (batch[mid] < b) lo = mid + 1; else hi = mid;
    }
    lb[b] = lo;
  }
  __syncthreads();
  if (b < NB) cnts[b] = (float)(lb[b + 1] - lb[b]);
}

// ---------------- pass2 + pool: segmented sum over sorted batch -------------
// h2s rows pre-scaled by dinv_src; 8 gathers in flight; flush on boundary.
__global__ __launch_bounds__(256) void k_agg2pool(const int* __restrict__ row_ptr,
                                                  const int* __restrict__ sidx,
                                                  const float* __restrict__ dinv,
                                                  const int* __restrict__ batch,
                                                  const unsigned short* __restrict__ h2s,
                                                  float* __restrict__ out_sums) {
  __shared__ float lds[NB * FO];  // 16KB
  for (int i = threadIdx.x; i < NB * FO; i += 256) lds[i] = 0.f;
  __syncthreads();

  int lane = threadIdx.x & 63;
  int gw = (blockIdx.x * 256 + threadIdx.x) >> 6;
  int ngw = (gridDim.x * 256) >> 6;
  int chunk = (NN + ngw - 1) / ngw;
  int n0 = __builtin_amdgcn_readfirstlane(gw * chunk);
  int n1 = min(NN, n0 + chunk);

  int bcur = -1;
  float acc = 0.f;
  for (int d = n0; d < n1; d++) {
    int b = batch[d];
    if (b != bcur) {
      if (bcur >= 0) atomicAdd(&lds[bcur * FO + lane], acc);
      bcur = b;
      acc = 0.f;
    }
    float a = bf16f(h2s[(size_t)d * FO + lane]);  // self-loop (pre-scaled)
    int rp0 = row_ptr[d], rp1 = row_ptr[d + 1];
    int j = rp0;
    for (; j + 8 <= rp1; j += 8) {
      int4 ia = *(const int4*)(sidx + j);
      int4 ib = *(const int4*)(sidx + j + 4);
      float g0 = bf16f(h2s[(size_t)ia.x * FO + lane]);
      float g1 = bf16f(h2s[(size_t)ia.y * FO + lane]);
      float g2 = bf16f(h2s[(size_t)ia.z * FO + lane]);
      float g3 = bf16f(h2s[(size_t)ia.w * FO + lane]);
      float g4 = bf16f(h2s[(size_t)ib.x * FO + lane]);
      float g5 = bf16f(h2s[(size_t)ib.y * FO + lane]);
      float g6 = bf16f(h2s[(size_t)ib.z * FO + lane]);
      float g7 = bf16f(h2s[(size_t)ib.w * FO + lane]);
      a += ((g0 + g1) + (g2 + g3)) + ((g4 + g5) + (g6 + g7));
    }
    for (; j < rp1; j++)
      a += bf16f(h2s[(size_t)sidx[j] * FO + lane]);
    acc += dinv[d] * a;
  }
  if (bcur >= 0) atomicAdd(&lds[bcur * FO + lane], acc);

  __syncthreads();
  for (int i = threadIdx.x; i < NB * FO; i += 256) {
    float v = lds[i];
    if (v != 0.f) atomicAdd(&out_sums[i], v);
  }
}

// ---------------- final: mean + bias ----------------------------------------
__global__ __launch_bounds__(256) void k_final(const float* __restrict__ out_sums,
                                               const float* __restrict__ cnts,
                                               const float* __restrict__ b2,
                                               float* __restrict__ out) {
  int i = blockIdx.x * 256 + threadIdx.x;
  if (i < NB * FO) {
    int b = i >> 6, j = i & 63;
    out[i] = out_sums[i] / fmaxf(cnts[b], 1.0f) + b2[j];
  }
}

extern "C" void kernel_launch(void* const* d_in, const int* in_sizes, int n_in,
                              void* d_out, int out_size, void* d_ws, size_t ws_size,
                              hipStream_t stream) {
  const float* x = (const float*)d_in[0];
  const int* ei = (const int*)d_in[1];     // [2,E] int32
  const int* batch = (const int*)d_in[2];  // [N] int32 (sorted)
  const float* W1 = (const float*)d_in[3];
  const float* b1 = (const float*)d_in[4];
  const float* W2 = (const float*)d_in[5];
  const float* b2 = (const float*)d_in[6];
  float* out = (float*)d_out;

  const int* es = ei;       // src
  const int* ed = ei + NE;  // dst

  // workspace: degi 0.4M | dinv 0.4M | row_ptr 0.4M | cursor 0.4M | blksum |
  // sidx 6.4M | xbs 12.8M | aggx 25.6M (reused as h2s) | h1b 25.6M |
  // out_sums | cnts  => ~72 MB
  char* w = (char*)d_ws;
  int*    degi    = (int*)w;       w += 100032 * 4;
  float*  dinv    = (float*)w;     w += 100032 * 4;
  int*    row_ptr = (int*)w;       w += 100032 * 4;
  int*    cursor  = (int*)w;       w += 100032 * 4;
  int*    blksum  = (int*)w;       w += 128 * 4;
  int*    sidx    = (int*)w;       w += (size_t)NE * 4;
  unsigned* xbs   = (unsigned*)w;  w += (size_t)100032 * FI * 2;
  float*  aggx    = (float*)w;     w += (size_t)100032 * FI * 4;
  unsigned* h1b   = (unsigned*)w;  w += (size_t)100032 * (FH / 2) * 4;
  float*  out_sums = (float*)w;    w += 4096 * 4;
  float*  cnts    = (float*)w;
  unsigned* h2s = (unsigned*)aggx;  // aggx dead after gemm1

  k_init<<<391, 256, 0, stream>>>(degi, out_sums);
  k_deg<<<1024, 256, 0, stream>>>(ed, degi);
  k_dinv<<<391, 256, 0, stream>>>(degi, dinv);
  k_xscale<<<3125, 256, 0, stream>>>(x, dinv, xbs);
  k_scan1<<<SCAN_BLKS, 1024, 0, stream>>>(degi, row_ptr, blksum);
  k_scan2<<<1, 128, 0, stream>>>(blksum);
  k_scan3<<<SCAN_BLKS, 1024, 0, stream>>>(row_ptr, blksum, cursor);
  k_place<<<1024, 256, 0, stream>>>(es, ed, cursor, sidx);
  k_agg1<<<2048, 256, 0, stream>>>(row_ptr, sidx, dinv, (const unsigned short*)xbs, aggx);
  k_gemm1<<<(NN + 63) / 64, 256, 0, stream>>>(aggx, W1, b1, h1b);
  k_gemm2<<<(NN + 63) / 64, 256, 0, stream>>>(h1b, W2, dinv, h2s);
  k_cnt_bs<<<1, 128, 0, stream>>>(batch, cnts);
  k_agg2pool<<<2048, 256, 0, stream>>>(row_ptr, sidx, dinv, batch,
                                       (const unsigned short*)h2s, out_sums);
  k_final<<<16, 256, 0, stream>>>(out_sums, cnts, b2, out);
}

// Round 14
// 410.756 us; speedup vs baseline: 3.2057x; 1.1202x over previous
//
#include <hip/hip_runtime.h>

// GCN encoder: 2x GCNConv (symmetric norm, self-loops) + global mean pool.
// N=100000, E=1600000, F_IN=64, H=128, O=64, B=64.
//
// R3:  k_cnt atomics -> binary search (-623us, matched).
// R7:  seq reads, time flat => per-edge atomic wall (~50ns serialized).
// R8:  dst-sorted + register accumulation + plain stores: 1317 -> 552us.
// R10: bf16 rows: FETCH halved, time flat => request-rate-bound.
// R12: folded dinv + 8-deep unroll + 2x occupancy: aggs out of top-5 (460us).
//      k_place WRITE stayed 105MB with 4B payload => partial-line dirty
//      writeback across XCDs (writes to one line come from all 8 XCDs).
// R13: XCD-partitioned placement: xcd = blockIdx&7 owns dst range
//      [xcd*12500,(xcd+1)*12500); its blocks scan all edges, place only
//      their range. All writes to a line from ONE XCD -> lines fill in
//      local L2 -> WRITE ~6.4MB. Extra reads (8x102MB) are L3 hits.

#define NN 100000
#define NE 1600000
#define FI 64
#define FH 128
#define FO 64
#define NB 64
#define SCAN_BLKS 98  // ceil(100000/1024)

// ---------------- bf16 helpers ----------------------------------------------
__device__ __forceinline__ unsigned bf16rn(float f) {
  unsigned u = __float_as_uint(f);
  return (u + 0x7fffu + ((u >> 16) & 1u)) >> 16;
}
__device__ __forceinline__ float bf16lo(unsigned u) { return __uint_as_float(u << 16); }
__device__ __forceinline__ float bf16hi(unsigned u) { return __uint_as_float(u & 0xffff0000u); }
__device__ __forceinline__ float bf16f(unsigned short u) {
  return __uint_as_float((unsigned)u << 16);
}

// ---------------- init: zero int-degree, pooled sums ------------------------
__global__ __launch_bounds__(256) void k_init(int* __restrict__ degi,
                                              float* __restrict__ out_sums) {
  int i = blockIdx.x * 256 + threadIdx.x;
  if (i < NN) degi[i] = 0;
  if (i < NB * FO) out_sums[i] = 0.0f;
}

// ---------------- in-degree over dst (= sort histogram) ---------------------
__global__ __launch_bounds__(256) void k_deg(const int* __restrict__ ed,
                                             int* __restrict__ degi) {
  int stride = gridDim.x * 256;
  for (int e = blockIdx.x * 256 + threadIdx.x; e < NE; e += stride)
    atomicAdd(&degi[ed[e]], 1);
}

// ---------------- dinv = rsqrt(1+indeg) (degi preserved for scan) -----------
__global__ __launch_bounds__(256) void k_dinv(const int* __restrict__ degi,
                                              float* __restrict__ dinv) {
  int i = blockIdx.x * 256 + threadIdx.x;
  if (i < NN) dinv[i] = rsqrtf(1.0f + (float)degi[i]);
}

// ---------------- xbs = bf16(x * dinv_row): dinv_src folded into rows --------
__global__ __launch_bounds__(256) void k_xscale(const float* __restrict__ x,
                                                const float* __restrict__ dinv,
                                                unsigned* __restrict__ xbs) {  // bf16 pairs
  int i = blockIdx.x * 256 + threadIdx.x;  // 8 elems per thread
  if (i < NN * FI / 8) {
    int node = i >> 3;
    float di = dinv[node];
    float4 v0 = ((const float4*)x)[2 * i];
    float4 v1 = ((const float4*)x)[2 * i + 1];
    uint4 q;
    q.x = bf16rn(v0.x * di) | (bf16rn(v0.y * di) << 16);
    q.y = bf16rn(v0.z * di) | (bf16rn(v0.w * di) << 16);
    q.z = bf16rn(v1.x * di) | (bf16rn(v1.y * di) << 16);
    q.w = bf16rn(v1.z * di) | (bf16rn(v1.w * di) << 16);
    ((uint4*)xbs)[i] = q;
  }
}

// ---------------- exclusive scan of degi -> row_ptr, cursor ------------------
__global__ __launch_bounds__(1024) void k_scan1(const int* __restrict__ hist,
                                                int* __restrict__ row_ptr,
                                                int* __restrict__ blksum) {
  __shared__ int s[1024];
  int tid = threadIdx.x;
  int i = blockIdx.x * 1024 + tid;
  int v = (i < NN) ? hist[i] : 0;
  s[tid] = v;
  __syncthreads();
  for (int off = 1; off < 1024; off <<= 1) {
    int t = (tid >= off) ? s[tid - off] : 0;
    __syncthreads();
    s[tid] += t;
    __syncthreads();
  }
  if (i < NN) row_ptr[i] = s[tid] - v;
  if (tid == 1023) blksum[blockIdx.x] = s[1023];
}

__global__ __launch_bounds__(128) void k_scan2(int* __restrict__ blksum) {
  if (threadIdx.x == 0) {
    int run = 0;
    for (int i = 0; i < SCAN_BLKS; i++) { int t = blksum[i]; blksum[i] = run; run += t; }
  }
}

__global__ __launch_bounds__(1024) void k_scan3(int* __restrict__ row_ptr,
                                                const int* __restrict__ blksum,
                                                int* __restrict__ cursor) {
  int i = blockIdx.x * 1024 + threadIdx.x;
  if (i < NN) {
    int rp = row_ptr[i] + blksum[blockIdx.x];
    row_ptr[i] = rp;
    cursor[i] = rp;
  }
  if (i == 0) row_ptr[NN] = NE;
}

// ---------------- placement, XCD-partitioned by dst range -------------------
// xcd = blockIdx&7 (HW round-robin heuristic; wrong mapping = slower, never
// incorrect). Each XCD's 128 blocks scan all edges, place only dst in
// [xcd*12500, ..+12500). All writes to a sidx line from one XCD -> full
// lines in local L2 -> writeback ~6.4MB instead of 105MB.
__global__ __launch_bounds__(256) void k_place(const int* __restrict__ es,
                                               const int* __restrict__ ed,
                                               int* __restrict__ cursor,
                                               int* __restrict__ sidx) {
  int xcd = blockIdx.x & 7;
  int grp = blockIdx.x >> 3;
  int ngrp = gridDim.x >> 3;
  int lo = xcd * (NN / 8);
  int hi = lo + (NN / 8);
  int stride = ngrp * 256;
  for (int e = grp * 256 + threadIdx.x; e < NE; e += stride) {
    int d = ed[e];
    if (d >= lo && d < hi) {
      int pos = atomicAdd(&cursor[d], 1);
      sidx[pos] = es[e];
    }
  }
}

// ---------------- pass1: aggx[d] = dinv_d*(xbs[d] + sum xbs[s]) --------------
// wave per dst row; 8 independent gathers in flight; plain store.
__global__ __launch_bounds__(256) void k_agg1(const int* __restrict__ row_ptr,
                                              const int* __restrict__ sidx,
                                              const float* __restrict__ dinv,
                                              const unsigned short* __restrict__ xbs,
                                              float* __restrict__ aggx) {
  int lane = threadIdx.x & 63;
  int wid = (blockIdx.x * 256 + threadIdx.x) >> 6;
  int nw = (gridDim.x * 256) >> 6;
  for (int dd0 = wid; dd0 < NN; dd0 += nw) {
    int d = __builtin_amdgcn_readfirstlane(dd0);
    float acc = bf16f(xbs[(size_t)d * FI + lane]);  // self-loop (pre-scaled)
    int rp0 = row_ptr[d], rp1 = row_ptr[d + 1];
    int j = rp0;
    for (; j + 8 <= rp1; j += 8) {
      int4 ia = *(const int4*)(sidx + j);
      int4 ib = *(const int4*)(sidx + j + 4);
      float g0 = bf16f(xbs[(size_t)ia.x * FI + lane]);
      float g1 = bf16f(xbs[(size_t)ia.y * FI + lane]);
      float g2 = bf16f(xbs[(size_t)ia.z * FI + lane]);
      float g3 = bf16f(xbs[(size_t)ia.w * FI + lane]);
      float g4 = bf16f(xbs[(size_t)ib.x * FI + lane]);
      float g5 = bf16f(xbs[(size_t)ib.y * FI + lane]);
      float g6 = bf16f(xbs[(size_t)ib.z * FI + lane]);
      float g7 = bf16f(xbs[(size_t)ib.w * FI + lane]);
      acc += ((g0 + g1) + (g2 + g3)) + ((g4 + g5) + (g6 + g7));
    }
    for (; j < rp1; j++)
      acc += bf16f(xbs[(size_t)sidx[j] * FI + lane]);
    aggx[(size_t)d * FI + lane] = dinv[d] * acc;
  }
}

// ---------------- GEMM1: h1 = relu(aggx @ W1 + b1) -> bf16 ------------------
__global__ __launch_bounds__(256) void k_gemm1(const float* __restrict__ X,
                                               const float* __restrict__ W,
                                               const float* __restrict__ bias,
                                               unsigned* __restrict__ Y) {  // bf16 pairs
  __shared__ float XsT[FI][64];
  __shared__ float Ws[FI][FH];
  int tid = threadIdx.x;
  int row0 = blockIdx.x * 64;

  for (int i = tid; i < FI * FH / 4; i += 256)
    ((float4*)&Ws[0][0])[i] = ((const float4*)W)[i];

  for (int i = tid; i < 64 * (FI / 4); i += 256) {
    int c4 = i & 15;
    int r = i >> 4;
    int row = row0 + r;
    float4 v = (row < NN) ? ((const float4*)X)[row * (FI / 4) + c4]
                          : make_float4(0.f, 0.f, 0.f, 0.f);
    XsT[c4 * 4 + 0][r] = v.x; XsT[c4 * 4 + 1][r] = v.y;
    XsT[c4 * 4 + 2][r] = v.z; XsT[c4 * 4 + 3][r] = v.w;
  }
  __syncthreads();

  int tr = tid & 15, tc = tid >> 4;
  float acc[4][8];
#pragma unroll
  for (int i = 0; i < 4; i++)
#pragma unroll
    for (int j = 0; j < 8; j++) acc[i][j] = 0.f;

#pragma unroll 8
  for (int k = 0; k < FI; k++) {
    float4 a = *(const float4*)&XsT[k][tr * 4];
    float4 w0 = *(const float4*)&Ws[k][tc * 8];
    float4 w1 = *(const float4*)&Ws[k][tc * 8 + 4];
    float av[4] = {a.x, a.y, a.z, a.w};
    float wv[8] = {w0.x, w0.y, w0.z, w0.w, w1.x, w1.y, w1.z, w1.w};
#pragma unroll
    for (int i = 0; i < 4; i++)
#pragma unroll
      for (int j = 0; j < 8; j++) acc[i][j] += av[i] * wv[j];
  }

  float4 bv0 = *(const float4*)&bias[tc * 8];
  float4 bv1 = *(const float4*)&bias[tc * 8 + 4];
  float bb[8] = {bv0.x, bv0.y, bv0.z, bv0.w, bv1.x, bv1.y, bv1.z, bv1.w};
#pragma unroll
  for (int i = 0; i < 4; i++) {
    int row = row0 + tr * 4 + i;
    if (row < NN) {
      unsigned o[4];
#pragma unroll
      for (int j = 0; j < 4; j++) {
        float v0 = acc[i][2 * j] + bb[2 * j];
        float v1 = acc[i][2 * j + 1] + bb[2 * j + 1];
        v0 = v0 > 0.f ? v0 : 0.f;
        v1 = v1 > 0.f ? v1 : 0.f;
        o[j] = bf16rn(v0) | (bf16rn(v1) << 16);
      }
      *(uint4*)&Y[(size_t)row * 64 + tc * 4] = make_uint4(o[0], o[1], o[2], o[3]);
    }
  }
}

// ---------------- GEMM2: h2s = (h1(bf16) @ W2) * dinv_row -> bf16 ------------
__global__ __launch_bounds__(256) void k_gemm2(const unsigned* __restrict__ Xb,
                                               const float* __restrict__ W,
                                               const float* __restrict__ dinv,
                                               unsigned* __restrict__ Yb) {  // bf16 pairs
  __shared__ float XsT[FH][64];
  __shared__ float Ws[FH][FO];
  int tid = threadIdx.x;
  int row0 = blockIdx.x * 64;

  for (int i = tid; i < FH * FO / 4; i += 256)
    ((float4*)&Ws[0][0])[i] = ((const float4*)W)[i];

  for (int i = tid; i < 64 * (FH / 8); i += 256) {
    int c8 = (i & 15) * 8;
    int r = i >> 4;
    int row = row0 + r;
    uint4 q = (row < NN) ? *(const uint4*)&Xb[(size_t)row * 64 + (c8 >> 1)]
                         : make_uint4(0, 0, 0, 0);
    XsT[c8 + 0][r] = bf16lo(q.x); XsT[c8 + 1][r] = bf16hi(q.x);
    XsT[c8 + 2][r] = bf16lo(q.y); XsT[c8 + 3][r] = bf16hi(q.y);
    XsT[c8 + 4][r] = bf16lo(q.z); XsT[c8 + 5][r] = bf16hi(q.z);
    XsT[c8 + 6][r] = bf16lo(q.w); XsT[c8 + 7][r] = bf16hi(q.w);
  }
  __syncthreads();

  int tr = tid & 15, tc = tid >> 4;
  float acc[4][4];
#pragma unroll
  for (int i = 0; i < 4; i++)
#pragma unroll
    for (int j = 0; j < 4; j++) acc[i][j] = 0.f;

#pragma unroll 8
  for (int k = 0; k < FH; k++) {
    float4 a = *(const float4*)&XsT[k][tr * 4];
    float4 w = *(const float4*)&Ws[k][tc * 4];
    float av[4] = {a.x, a.y, a.z, a.w};
    float wv[4] = {w.x, w.y, w.z, w.w};
#pragma unroll
    for (int i = 0; i < 4; i++)
#pragma unroll
      for (int j = 0; j < 4; j++) acc[i][j] += av[i] * wv[j];
  }

#pragma unroll
  for (int i = 0; i < 4; i++) {
    int row = row0 + tr * 4 + i;
    if (row < NN) {
      float dd = dinv[row];
      uint2 o;
      o.x = bf16rn(acc[i][0] * dd) | (bf16rn(acc[i][1] * dd) << 16);
      o.y = bf16rn(acc[i][2] * dd) | (bf16rn(acc[i][3] * dd) << 16);
      *(uint2*)&Yb[(size_t)row * 32 + tc * 2] = o;
    }
  }
}

// ---------------- node counts per graph: binary search on SORTED batch ------
__global__ __launch_bounds__(128) void k_cnt_bs(const int* __restrict__ batch,
                                                float* __restrict__ cnts) {
  __shared__ int lb[NB + 1];
  int b = threadIdx.x;
  if (b <= NB) {
    int lo = 0, hi = NN;
    while (lo < hi) {
      int mid = (lo + hi) >> 1;
      if (batch[mid] < b) lo = mid + 1; else hi = mid;
    }
    lb[b] = lo;
  }
  __syncthreads();
  if (b < NB) cnts[b] = (float)(lb[b + 1] - lb[b]);
}

// ---------------- pass2 + pool: segmented sum over sorted batch -------------
__global__ __launch_bounds__(256) void k_agg2pool(const int* __restrict__ row_ptr,
                                                  const int* __restrict__ sidx,
                                                  const float* __restrict__ dinv,
                                                  const int* __restrict__ batch,
                                                  const unsigned short* __restrict__ h2s,
                                                  float* __restrict__ out_sums) {
  __shared__ float lds[NB * FO];  // 16KB
  for (int i = threadIdx.x; i < NB * FO; i += 256) lds[i] = 0.f;
  __syncthreads();

  int lane = threadIdx.x & 63;
  int gw = (blockIdx.x * 256 + threadIdx.x) >> 6;
  int ngw = (gridDim.x * 256) >> 6;
  int chunk = (NN + ngw - 1) / ngw;
  int n0 = __builtin_amdgcn_readfirstlane(gw * chunk);
  int n1 = min(NN, n0 + chunk);

  int bcur = -1;
  float acc = 0.f;
  for (int d = n0; d < n1; d++) {
    int b = batch[d];
    if (b != bcur) {
      if (bcur >= 0) atomicAdd(&lds[bcur * FO + lane], acc);
      bcur = b;
      acc = 0.f;
    }
    float a = bf16f(h2s[(size_t)d * FO + lane]);  // self-loop (pre-scaled)
    int rp0 = row_ptr[d], rp1 = row_ptr[d + 1];
    int j = rp0;
    for (; j + 8 <= rp1; j += 8) {
      int4 ia = *(const int4*)(sidx + j);
      int4 ib = *(const int4*)(sidx + j + 4);
      float g0 = bf16f(h2s[(size_t)ia.x * FO + lane]);
      float g1 = bf16f(h2s[(size_t)ia.y * FO + lane]);
      float g2 = bf16f(h2s[(size_t)ia.z * FO + lane]);
      float g3 = bf16f(h2s[(size_t)ia.w * FO + lane]);
      float g4 = bf16f(h2s[(size_t)ib.x * FO + lane]);
      float g5 = bf16f(h2s[(size_t)ib.y * FO + lane]);
      float g6 = bf16f(h2s[(size_t)ib.z * FO + lane]);
      float g7 = bf16f(h2s[(size_t)ib.w * FO + lane]);
      a += ((g0 + g1) + (g2 + g3)) + ((g4 + g5) + (g6 + g7));
    }
    for (; j < rp1; j++)
      a += bf16f(h2s[(size_t)sidx[j] * FO + lane]);
    acc += dinv[d] * a;
  }
  if (bcur >= 0) atomicAdd(&lds[bcur * FO + lane], acc);

  __syncthreads();
  for (int i = threadIdx.x; i < NB * FO; i += 256) {
    float v = lds[i];
    if (v != 0.f) atomicAdd(&out_sums[i], v);
  }
}

// ---------------- final: mean + bias ----------------------------------------
__global__ __launch_bounds__(256) void k_final(const float* __restrict__ out_sums,
                                               const float* __restrict__ cnts,
                                               const float* __restrict__ b2,
                                               float* __restrict__ out) {
  int i = blockIdx.x * 256 + threadIdx.x;
  if (i < NB * FO) {
    int b = i >> 6, j = i & 63;
    out[i] = out_sums[i] / fmaxf(cnts[b], 1.0f) + b2[j];
  }
}

extern "C" void kernel_launch(void* const* d_in, const int* in_sizes, int n_in,
                              void* d_out, int out_size, void* d_ws, size_t ws_size,
                              hipStream_t stream) {
  const float* x = (const float*)d_in[0];
  const int* ei = (const int*)d_in[1];     // [2,E] int32
  const int* batch = (const int*)d_in[2];  // [N] int32 (sorted)
  const float* W1 = (const float*)d_in[3];
  const float* b1 = (const float*)d_in[4];
  const float* W2 = (const float*)d_in[5];
  const float* b2 = (const float*)d_in[6];
  float* out = (float*)d_out;

  const int* es = ei;       // src
  const int* ed = ei + NE;  // dst

  // workspace: degi 0.4M | dinv 0.4M | row_ptr 0.4M | cursor 0.4M | blksum |
  // sidx 6.4M | xbs 12.8M | aggx 25.6M (reused as h2s) | h1b 25.6M |
  // out_sums | cnts  => ~72 MB
  char* w = (char*)d_ws;
  int*    degi    = (int*)w;       w += 100032 * 4;
  float*  dinv    = (float*)w;     w += 100032 * 4;
  int*    row_ptr = (int*)w;       w += 100032 * 4;
  int*    cursor  = (int*)w;       w += 100032 * 4;
  int*    blksum  = (int*)w;       w += 128 * 4;
  int*    sidx    = (int*)w;       w += (size_t)NE * 4;
  unsigned* xbs   = (unsigned*)w;  w += (size_t)100032 * FI * 2;
  float*  aggx    = (float*)w;     w += (size_t)100032 * FI * 4;
  unsigned* h1b   = (unsigned*)w;  w += (size_t)100032 * (FH / 2) * 4;
  float*  out_sums = (float*)w;    w += 4096 * 4;
  float*  cnts    = (float*)w;
  unsigned* h2s = (unsigned*)aggx;  // aggx dead after gemm1

  k_init<<<391, 256, 0, stream>>>(degi, out_sums);
  k_deg<<<1024, 256, 0, stream>>>(ed, degi);
  k_dinv<<<391, 256, 0, stream>>>(degi, dinv);
  k_xscale<<<3125, 256, 0, stream>>>(x, dinv, xbs);
  k_scan1<<<SCAN_BLKS, 1024, 0, stream>>>(degi, row_ptr, blksum);
  k_scan2<<<1, 128, 0, stream>>>(blksum);
  k_scan3<<<SCAN_BLKS, 1024, 0, stream>>>(row_ptr, blksum, cursor);
  k_place<<<1024, 256, 0, stream>>>(es, ed, cursor, sidx);
  k_agg1<<<2048, 256, 0, stream>>>(row_ptr, sidx, dinv, (const unsigned short*)xbs, aggx);
  k_gemm1<<<(NN + 63) / 64, 256, 0, stream>>>(aggx, W1, b1, h1b);
  k_gemm2<<<(NN + 63) / 64, 256, 0, stream>>>(h1b, W2, dinv, h2s);
  k_cnt_bs<<<1, 128, 0, stream>>>(batch, cnts);
  k_agg2pool<<<2048, 256, 0, stream>>>(row_ptr, sidx, dinv, batch,
                                       (const unsigned short*)h2s, out_sums);
  k_final<<<16, 256, 0, stream>>>(out_sums, cnts, b2, out);
}